// Round 12
// baseline (188.837 us; speedup 1.0000x reference)
//
#include <hip/hip_runtime.h>
#include <hip/hip_bf16.h>
#include <cstdint>
#include <cstddef>

#define N_ROWS 8192
#define HDIM 512
#define INDIM 128
#define NHEADS 4
#define NNB 8

typedef __bf16 bf16_t;
typedef __bf16 bf16x8 __attribute__((ext_vector_type(8)));
typedef __bf16 bf16x4 __attribute__((ext_vector_type(4)));
typedef __bf16 bf16x2 __attribute__((ext_vector_type(2)));
typedef float f32x4 __attribute__((ext_vector_type(4)));

__device__ __forceinline__ float sigmoidf_(float x) { return 1.0f / (1.0f + expf(-x)); }

__device__ __forceinline__ void load_lds16(const void* g, void* l) {
  __builtin_amdgcn_global_load_lds(
      (const __attribute__((address_space(1))) void*)g,
      (__attribute__((address_space(3))) void*)l, 16, 0, 0);
}

// ---------------------------------------------------------------------------
// Pack (vectorized 4-wide): W1 = bf16([w_fg; w_ig]) (1024 x 2048),
//   W2i = bf16 gate-interleaved [w_ih | w_hh] (2048 x 640), row' = q*4+g,
//   b2[c'] = b_ih + b_hh (interleaved), A2[:, 0:128] = bf16(x)
// ---------------------------------------------------------------------------
__global__ __launch_bounds__(256) void pack_kernel(
    const float* __restrict__ w_fg, const float* __restrict__ w_ig,
    const float* __restrict__ w_ih, const float* __restrict__ w_hh,
    const float* __restrict__ b_ih, const float* __restrict__ b_hh,
    const float* __restrict__ x,
    bf16_t* __restrict__ W1, bf16_t* __restrict__ W2i,
    float* __restrict__ b2, bf16_t* __restrict__ A2)
{
  int idx = blockIdx.x * 256 + threadIdx.x;
  if (idx < 524288) {                       // W1: 4 elems/thread
    const int e = idx * 4, r = e >> 11, k = e & 2047;
    const float* src = (r < 512) ? &w_fg[(size_t)r * 2048 + k]
                                 : &w_ig[(size_t)(r - 512) * 2048 + k];
    const float4 v = *(const float4*)src;
    bf16x4 o; o[0] = (bf16_t)v.x; o[1] = (bf16_t)v.y; o[2] = (bf16_t)v.z; o[3] = (bf16_t)v.w;
    *(bf16x4*)&W1[e] = o;
    return;
  }
  idx -= 524288;
  if (idx < 327680) {                       // W2i: 4 elems/thread
    const int e = idx * 4, r = e / 640, k = e - r * 640;   // k multiple of 4
    const int rp = (r & 511) * 4 + (r >> 9);
    const float* src = (k < 128) ? &w_ih[(size_t)r * 128 + k]
                                 : &w_hh[(size_t)r * 512 + (k - 128)];
    const float4 v = *(const float4*)src;
    bf16x4 o; o[0] = (bf16_t)v.x; o[1] = (bf16_t)v.y; o[2] = (bf16_t)v.z; o[3] = (bf16_t)v.w;
    *(bf16x4*)&W2i[(size_t)rp * 640 + k] = o;
    return;
  }
  idx -= 327680;
  if (idx < 2048) {                         // b2
    const int q = idx >> 2, g = idx & 3;
    b2[idx] = b_ih[g * 512 + q] + b_hh[g * 512 + q];
    return;
  }
  idx -= 2048;
  if (idx < 262144) {                       // x -> A2[:, :128]
    const int e = idx * 4, n = e >> 7, cc = e & 127;
    const float4 v = *(const float4*)&x[e];
    bf16x4 o; o[0] = (bf16_t)v.x; o[1] = (bf16_t)v.y; o[2] = (bf16_t)v.z; o[3] = (bf16_t)v.w;
    *(bf16x4*)&A2[(size_t)n * 640 + cc] = o;
  }
}

// ---------------------------------------------------------------------------
// Attention + aggregation: per-row softmax over 8 neighbors, agg -> bf16
// ---------------------------------------------------------------------------
__global__ __launch_bounds__(256) void attn_agg_kernel(
    const float* __restrict__ h, const float* __restrict__ hs,
    const float* __restrict__ a_src, bf16_t* __restrict__ agg)
{
  __shared__ float s_hs[NNB][HDIM];
  __shared__ float s_h[HDIM];
  __shared__ float s_logit[NNB][NHEADS];
  __shared__ float s_self[NHEADS];

  const int n = blockIdx.x;
  const int t = threadIdx.x;
  const float* hs_n = hs + (size_t)n * (NNB * HDIM);
  const float* h_n  = h  + (size_t)n * HDIM;

  {
    const float4* s4 = (const float4*)hs_n;
    float4* d4 = (float4*)&s_hs[0][0];
#pragma unroll
    for (int i = 0; i < 4; ++i) d4[t + i * 256] = s4[t + i * 256];
    if (t < HDIM / 4) ((float4*)s_h)[t] = ((const float4*)h_n)[t];
  }
  __syncthreads();

  const int wave = t >> 6, lane = t & 63;
#pragma unroll
  for (int kk = 0; kk < 2; ++kk) {
    const int k = wave * 2 + kk;
    float acc0 = 0.f, acc1 = 0.f, acc2 = 0.f, acc3 = 0.f;
#pragma unroll
    for (int i = 0; i < HDIM / 64; ++i) {
      const int hh = i * 64 + lane;
      const float v = s_hs[k][hh];
      const float4 av = *(const float4*)(a_src + (size_t)(HDIM + hh) * NHEADS);
      acc0 += v * av.x; acc1 += v * av.y; acc2 += v * av.z; acc3 += v * av.w;
    }
    float accs[NHEADS] = {acc0, acc1, acc2, acc3};
#pragma unroll
    for (int m = 0; m < NHEADS; ++m) {
      float a = accs[m];
#pragma unroll
      for (int off = 32; off > 0; off >>= 1) a += __shfl_xor(a, off);
      if (lane == 0) s_logit[k][m] = a;
    }
  }
  if (wave == 0) {
    float acc0 = 0.f, acc1 = 0.f, acc2 = 0.f, acc3 = 0.f;
#pragma unroll
    for (int i = 0; i < HDIM / 64; ++i) {
      const int hh = i * 64 + lane;
      const float v = s_h[hh];
      const float4 av = *(const float4*)(a_src + (size_t)hh * NHEADS);
      acc0 += v * av.x; acc1 += v * av.y; acc2 += v * av.z; acc3 += v * av.w;
    }
    float accs[NHEADS] = {acc0, acc1, acc2, acc3};
#pragma unroll
    for (int m = 0; m < NHEADS; ++m) {
      float a = accs[m];
#pragma unroll
      for (int off = 32; off > 0; off >>= 1) a += __shfl_xor(a, off);
      if (lane == 0) s_self[m] = a;
    }
  }
  __syncthreads();

  float w[NNB][NHEADS];
#pragma unroll
  for (int m = 0; m < NHEADS; ++m) {
    const float sm = s_self[m];
    float mx = -1e30f;
#pragma unroll
    for (int k = 0; k < NNB; ++k) {
      float l = sm + s_logit[k][m];
      l = (l >= 0.f) ? l : 0.2f * l;
      w[k][m] = l;
      mx = fmaxf(mx, l);
    }
    float sum = 0.f;
#pragma unroll
    for (int k = 0; k < NNB; ++k) { const float e = expf(w[k][m] - mx); w[k][m] = e; sum += e; }
    const float inv = 1.f / sum;
#pragma unroll
    for (int k = 0; k < NNB; ++k) w[k][m] *= inv;
  }

  bf16_t* agg_n = agg + (size_t)n * (NHEADS * HDIM);
  const int hh = t * 2;
  float e0[NNB], e1[NNB];
#pragma unroll
  for (int k = 0; k < NNB; ++k) { e0[k] = s_hs[k][hh]; e1[k] = s_hs[k][hh + 1]; }
#pragma unroll
  for (int m = 0; m < NHEADS; ++m) {
    float a0 = 0.f, a1 = 0.f;
#pragma unroll
    for (int k = 0; k < NNB; ++k) { a0 += w[k][m] * e0[k]; a1 += w[k][m] * e1[k]; }
    bf16x2 pk; pk[0] = (bf16_t)a0; pk[1] = (bf16_t)a1;
    *(bf16x2*)(agg_n + m * HDIM + hh) = pk;
  }
}

// ---------------------------------------------------------------------------
// GEMM1 (spatial gates): BK=32 double-buffered, STAGE-ISSUED-EARLY:
//   for t { STAGE(buf^1, t+1); COMPUTE(buf); __syncthreads(); }
// The syncthreads drain (vmcnt 0) lands AFTER compute, so next-tile HBM
// latency elapses under the current tile's ds_read+MFMA. Plain __syncthreads,
// compiler-scheduled (no asm pinning). Tile 128x64, grid 64x16 = 1024 blocks.
// Round-10-verified 4-chunk XOR swizzle (conflicts == 0): physical chunk =
// q ^ ((row>>1)&3), pre-swizzled global source + linear LDS dest + same XOR
// on read. LDS 24 KB.
// ---------------------------------------------------------------------------
__global__ __launch_bounds__(256) void gemm1_kernel(
    const bf16_t* __restrict__ A, const bf16_t* __restrict__ Bt,
    const float* __restrict__ b_fg, const float* __restrict__ b_ig,
    const float* __restrict__ c_in, const float* __restrict__ h_in,
    float* __restrict__ cprime, bf16_t* __restrict__ A2)
{
  __shared__ bf16_t At[2][128][32];   // 16 KB
  __shared__ bf16_t Bs[2][64][32];    //  8 KB

  const int tid  = threadIdx.x;
  const int wave = tid >> 6, lane = tid & 63;
  const int wr = wave >> 1, wc = wave & 1;
  const int bm0 = blockIdx.x * 128;
  const int bn0 = blockIdx.y * 64;
  const int K = 2048;

  f32x4 acc[4][2] = {};

  const int srow = tid >> 2;                         // 0..63
  const int sch  = tid & 3;                          // physical 16B chunk
  const int gsw8 = (sch ^ ((srow >> 1) & 3)) * 8;    // pre-swizzled global chunk
  const int sch8 = sch * 8;                          // linear LDS dest
  const int frow = lane & 15;
  const int fro8 = ((lane >> 4) ^ ((frow >> 1) & 3)) * 8;  // swizzled read chunk

  auto STAGE = [&](int buf, int k0) {
    load_lds16(A  + (size_t)(bm0 + srow)      * K + k0 + gsw8, &At[buf][srow][sch8]);
    load_lds16(A  + (size_t)(bm0 + 64 + srow) * K + k0 + gsw8, &At[buf][64 + srow][sch8]);
    load_lds16(Bt + (size_t)(bn0 + srow)      * K + k0 + gsw8, &Bs[buf][srow][sch8]);
  };
  auto COMPUTE = [&](int buf) {
    bf16x8 af[4], bv[2];
#pragma unroll
    for (int i = 0; i < 4; ++i) af[i] = *(const bf16x8*)&At[buf][wr * 64 + i * 16 + frow][fro8];
#pragma unroll
    for (int j = 0; j < 2; ++j) bv[j] = *(const bf16x8*)&Bs[buf][wc * 32 + j * 16 + frow][fro8];
#pragma unroll
    for (int i = 0; i < 4; ++i)
#pragma unroll
      for (int j = 0; j < 2; ++j)
        acc[i][j] = __builtin_amdgcn_mfma_f32_16x16x32_bf16(af[i], bv[j], acc[i][j], 0, 0, 0);
  };

  const int nt = K >> 5;   // 64
  STAGE(0, 0);
  __syncthreads();
  for (int t = 0; t < nt; ++t) {
    if (t + 1 < nt) STAGE((t + 1) & 1, (t + 1) * 32);
    COMPUTE(t & 1);
    __syncthreads();
  }

  const int col_in = lane & 15;
  const int row_in = (lane >> 4) * 4;
#pragma unroll
  for (int i = 0; i < 4; ++i) {
#pragma unroll
    for (int j = 0; j < 2; ++j) {
      const int col = bn0 + wc * 32 + j * 16 + col_in;
#pragma unroll
      for (int r = 0; r < 4; ++r) {
        const int row = bm0 + wr * 64 + i * 16 + row_in + r;
        const float v = acc[i][j][r];
        if (col < 512) {
          const float s = sigmoidf_(v + b_fg[col]);
          cprime[(size_t)row * 512 + col] = c_in[(size_t)row * 512 + col] * s;
        } else {
          const int jj = col - 512;
          const float s = sigmoidf_(v + b_ig[jj]);
          A2[(size_t)row * 640 + 128 + jj] = (bf16_t)(h_in[(size_t)row * 512 + jj] * s);
        }
      }
    }
  }
}

// ---------------------------------------------------------------------------
// GEMM2 (LSTM gates, fused finish): BK=32 double-buffered stage-early, tile
// 128x128, grid 64x16. Same 4-chunk swizzle. Cols gate-interleaved (c=q*4+g).
// Fused LSTM epilogue via two-pass fp32 LDS exchange (union, 32 KB total).
// ---------------------------------------------------------------------------
__global__ __launch_bounds__(256) void gemm2_kernel(
    const bf16_t* __restrict__ A, const bf16_t* __restrict__ Bt,
    const float* __restrict__ b2, const float* __restrict__ cprime,
    float* __restrict__ out)
{
  __shared__ union {
    struct { bf16_t A[2][128][32]; bf16_t B[2][128][32]; } st;  // 32 KB
    float epi[64][128];                                         // 32 KB
  } sm;

  const int tid  = threadIdx.x;
  const int wave = tid >> 6, lane = tid & 63;
  const int wr = wave >> 1, wc = wave & 1;
  const int bm0 = blockIdx.x * 128;
  const int bn0 = blockIdx.y * 128;
  const int K = 640;

  f32x4 acc[4][4] = {};

  const int srow = tid >> 2;
  const int sch  = tid & 3;
  const int gsw8 = (sch ^ ((srow >> 1) & 3)) * 8;
  const int sch8 = sch * 8;
  const int frow = lane & 15;
  const int fro8 = ((lane >> 4) ^ ((frow >> 1) & 3)) * 8;

  auto STAGE = [&](int buf, int k0) {
    load_lds16(A  + (size_t)(bm0 + srow)      * K + k0 + gsw8, &sm.st.A[buf][srow][sch8]);
    load_lds16(A  + (size_t)(bm0 + 64 + srow) * K + k0 + gsw8, &sm.st.A[buf][64 + srow][sch8]);
    load_lds16(Bt + (size_t)(bn0 + srow)      * K + k0 + gsw8, &sm.st.B[buf][srow][sch8]);
    load_lds16(Bt + (size_t)(bn0 + 64 + srow) * K + k0 + gsw8, &sm.st.B[buf][64 + srow][sch8]);
  };
  auto COMPUTE = [&](int buf) {
    bf16x8 af[4], bv[4];
#pragma unroll
    for (int i = 0; i < 4; ++i) af[i] = *(const bf16x8*)&sm.st.A[buf][wr * 64 + i * 16 + frow][fro8];
#pragma unroll
    for (int j = 0; j < 4; ++j) bv[j] = *(const bf16x8*)&sm.st.B[buf][wc * 64 + j * 16 + frow][fro8];
#pragma unroll
    for (int i = 0; i < 4; ++i)
#pragma unroll
      for (int j = 0; j < 4; ++j)
        acc[i][j] = __builtin_amdgcn_mfma_f32_16x16x32_bf16(af[i], bv[j], acc[i][j], 0, 0, 0);
  };

  const int nt = K >> 5;   // 20
  STAGE(0, 0);
  __syncthreads();
  for (int t = 0; t < nt; ++t) {
    if (t + 1 < nt) STAGE((t + 1) & 1, (t + 1) * 32);
    COMPUTE(t & 1);
    __syncthreads();
  }

  // Fused LSTM finish: two passes over 64-row halves through fp32 LDS.
  const int col_in = lane & 15;
  const int row_in = (lane >> 4) * 4;
  const int q0i = bn0 >> 2;           // first global q of this block (32 q's)
  const int qi  = tid & 31;           // 0..31
  const int r0  = tid >> 5;           // 0..7

#pragma unroll
  for (int p = 0; p < 2; ++p) {
    if (wr == p) {
#pragma unroll
      for (int i = 0; i < 4; ++i)
#pragma unroll
        for (int j = 0; j < 4; ++j)
#pragma unroll
          for (int r = 0; r < 4; ++r)
            sm.epi[i * 16 + row_in + r][wc * 64 + j * 16 + col_in] = acc[i][j][r];
    }
    __syncthreads();
    const float4 bb = *(const float4*)&b2[(size_t)(q0i + qi) * 4];
#pragma unroll
    for (int rr = 0; rr < 8; ++rr) {
      const int lr = r0 + rr * 8;               // 0..63 local row in this half
      const float4 g4 = *(const float4*)&sm.epi[lr][qi * 4];
      const int grow = bm0 + p * 64 + lr;
      const int q    = q0i + qi;
      const float cp = cprime[(size_t)grow * 512 + q];
      const float ig = sigmoidf_(g4.x + bb.x);
      const float fg = sigmoidf_(g4.y + bb.y);
      const float gg = tanhf(g4.z + bb.z);
      const float og = sigmoidf_(g4.w + bb.w);
      const float cn = fg * cp + ig * gg;
      const float hn = og * tanhf(cn);
      out[(size_t)grow * 512 + q] = hn;
      out[(size_t)N_ROWS * 512 + (size_t)grow * 512 + q] = cn;
    }
    __syncthreads();
  }
}

// ---------------------------------------------------------------------------
extern "C" void kernel_launch(void* const* d_in, const int* in_sizes, int n_in,
                              void* d_out, int out_size, void* d_ws, size_t ws_size,
                              hipStream_t stream) {
  const float* x     = (const float*)d_in[0];
  const float* h     = (const float*)d_in[1];
  const float* c     = (const float*)d_in[2];
  const float* hsp   = (const float*)d_in[3];
  const float* a_src = (const float*)d_in[4];
  const float* w_fg  = (const float*)d_in[5];
  const float* b_fg  = (const float*)d_in[6];
  const float* w_ig  = (const float*)d_in[7];
  const float* b_ig  = (const float*)d_in[8];
  const float* w_ih  = (const float*)d_in[9];
  const float* w_hh  = (const float*)d_in[10];
  const float* b_ih  = (const float*)d_in[11];
  const float* b_hh  = (const float*)d_in[12];
  float* out = (float*)d_out;

  uint8_t* ws = (uint8_t*)d_ws;
  bf16_t* agg    = (bf16_t*)(ws);                 // 8192*2048*2 = 33,554,432
  bf16_t* W1     = (bf16_t*)(ws + 33554432);      // 1024*2048*2 =  4,194,304
  bf16_t* W2i    = (bf16_t*)(ws + 37748736);      // 2048*640*2  =  2,621,440
  float*  b2     = (float*) (ws + 40370176);      // 2048*4      =      8,192
  bf16_t* A2     = (bf16_t*)(ws + 40378368);      // 8192*640*2  = 10,485,760
  float*  cprime = (float*) (ws + 50864128);      // 8192*512*4  = 16,777,216
  // total 67,641,344 bytes

  pack_kernel<<<4360, 256, 0, stream>>>(w_fg, w_ig, w_ih, w_hh, b_ih, b_hh, x,
                                        W1, W2i, b2, A2);
  attn_agg_kernel<<<N_ROWS, 256, 0, stream>>>(h, hsp, a_src, agg);
  gemm1_kernel<<<dim3(64, 16), 256, 0, stream>>>(
      agg, W1, b_fg, b_ig, c, h, cprime, A2);
  gemm2_kernel<<<dim3(64, 16), 256, 0, stream>>>(
      A2, W2i, b2, cprime, out);
}

// Round 14
// 186.551 us; speedup vs baseline: 1.0123x; 1.0123x over previous
//
#include <hip/hip_runtime.h>
#include <hip/hip_bf16.h>
#include <cstdint>
#include <cstddef>

#define N_ROWS 8192
#define HDIM 512
#define INDIM 128
#define NHEADS 4
#define NNB 8

typedef __bf16 bf16_t;
typedef __bf16 bf16x8 __attribute__((ext_vector_type(8)));
typedef __bf16 bf16x4 __attribute__((ext_vector_type(4)));
typedef __bf16 bf16x2 __attribute__((ext_vector_type(2)));
typedef float f32x4 __attribute__((ext_vector_type(4)));

__device__ __forceinline__ float sigmoidf_(float x) { return 1.0f / (1.0f + expf(-x)); }

__device__ __forceinline__ void load_lds16(const void* g, void* l) {
  __builtin_amdgcn_global_load_lds(
      (const __attribute__((address_space(1))) void*)g,
      (__attribute__((address_space(3))) void*)l, 16, 0, 0);
}

// ---------------------------------------------------------------------------
// Pack (vectorized 4-wide): W1 = bf16([w_fg; w_ig]) (1024 x 2048),
//   W2i = bf16 gate-interleaved [w_ih | w_hh] (2048 x 640), row' = q*4+g,
//   b2[c'] = b_ih + b_hh (interleaved), A2[:, 0:128] = bf16(x)
// ---------------------------------------------------------------------------
__global__ __launch_bounds__(256) void pack_kernel(
    const float* __restrict__ w_fg, const float* __restrict__ w_ig,
    const float* __restrict__ w_ih, const float* __restrict__ w_hh,
    const float* __restrict__ b_ih, const float* __restrict__ b_hh,
    const float* __restrict__ x,
    bf16_t* __restrict__ W1, bf16_t* __restrict__ W2i,
    float* __restrict__ b2, bf16_t* __restrict__ A2)
{
  int idx = blockIdx.x * 256 + threadIdx.x;
  if (idx < 524288) {                       // W1: 4 elems/thread
    const int e = idx * 4, r = e >> 11, k = e & 2047;
    const float* src = (r < 512) ? &w_fg[(size_t)r * 2048 + k]
                                 : &w_ig[(size_t)(r - 512) * 2048 + k];
    const float4 v = *(const float4*)src;
    bf16x4 o; o[0] = (bf16_t)v.x; o[1] = (bf16_t)v.y; o[2] = (bf16_t)v.z; o[3] = (bf16_t)v.w;
    *(bf16x4*)&W1[e] = o;
    return;
  }
  idx -= 524288;
  if (idx < 327680) {                       // W2i: 4 elems/thread
    const int e = idx * 4, r = e / 640, k = e - r * 640;   // k multiple of 4
    const int rp = (r & 511) * 4 + (r >> 9);
    const float* src = (k < 128) ? &w_ih[(size_t)r * 128 + k]
                                 : &w_hh[(size_t)r * 512 + (k - 128)];
    const float4 v = *(const float4*)src;
    bf16x4 o; o[0] = (bf16_t)v.x; o[1] = (bf16_t)v.y; o[2] = (bf16_t)v.z; o[3] = (bf16_t)v.w;
    *(bf16x4*)&W2i[(size_t)rp * 640 + k] = o;
    return;
  }
  idx -= 327680;
  if (idx < 2048) {                         // b2
    const int q = idx >> 2, g = idx & 3;
    b2[idx] = b_ih[g * 512 + q] + b_hh[g * 512 + q];
    return;
  }
  idx -= 2048;
  if (idx < 262144) {                       // x -> A2[:, :128]
    const int e = idx * 4, n = e >> 7, cc = e & 127;
    const float4 v = *(const float4*)&x[e];
    bf16x4 o; o[0] = (bf16_t)v.x; o[1] = (bf16_t)v.y; o[2] = (bf16_t)v.z; o[3] = (bf16_t)v.w;
    *(bf16x4*)&A2[(size_t)n * 640 + cc] = o;
  }
}

// ---------------------------------------------------------------------------
// Attention + aggregation: per-row softmax over 8 neighbors, agg -> bf16
// ---------------------------------------------------------------------------
__global__ __launch_bounds__(256) void attn_agg_kernel(
    const float* __restrict__ h, const float* __restrict__ hs,
    const float* __restrict__ a_src, bf16_t* __restrict__ agg)
{
  __shared__ float s_hs[NNB][HDIM];
  __shared__ float s_h[HDIM];
  __shared__ float s_logit[NNB][NHEADS];
  __shared__ float s_self[NHEADS];

  const int n = blockIdx.x;
  const int t = threadIdx.x;
  const float* hs_n = hs + (size_t)n * (NNB * HDIM);
  const float* h_n  = h  + (size_t)n * HDIM;

  {
    const float4* s4 = (const float4*)hs_n;
    float4* d4 = (float4*)&s_hs[0][0];
#pragma unroll
    for (int i = 0; i < 4; ++i) d4[t + i * 256] = s4[t + i * 256];
    if (t < HDIM / 4) ((float4*)s_h)[t] = ((const float4*)h_n)[t];
  }
  __syncthreads();

  const int wave = t >> 6, lane = t & 63;
#pragma unroll
  for (int kk = 0; kk < 2; ++kk) {
    const int k = wave * 2 + kk;
    float acc0 = 0.f, acc1 = 0.f, acc2 = 0.f, acc3 = 0.f;
#pragma unroll
    for (int i = 0; i < HDIM / 64; ++i) {
      const int hh = i * 64 + lane;
      const float v = s_hs[k][hh];
      const float4 av = *(const float4*)(a_src + (size_t)(HDIM + hh) * NHEADS);
      acc0 += v * av.x; acc1 += v * av.y; acc2 += v * av.z; acc3 += v * av.w;
    }
    float accs[NHEADS] = {acc0, acc1, acc2, acc3};
#pragma unroll
    for (int m = 0; m < NHEADS; ++m) {
      float a = accs[m];
#pragma unroll
      for (int off = 32; off > 0; off >>= 1) a += __shfl_xor(a, off);
      if (lane == 0) s_logit[k][m] = a;
    }
  }
  if (wave == 0) {
    float acc0 = 0.f, acc1 = 0.f, acc2 = 0.f, acc3 = 0.f;
#pragma unroll
    for (int i = 0; i < HDIM / 64; ++i) {
      const int hh = i * 64 + lane;
      const float v = s_h[hh];
      const float4 av = *(const float4*)(a_src + (size_t)hh * NHEADS);
      acc0 += v * av.x; acc1 += v * av.y; acc2 += v * av.z; acc3 += v * av.w;
    }
    float accs[NHEADS] = {acc0, acc1, acc2, acc3};
#pragma unroll
    for (int m = 0; m < NHEADS; ++m) {
      float a = accs[m];
#pragma unroll
      for (int off = 32; off > 0; off >>= 1) a += __shfl_xor(a, off);
      if (lane == 0) s_self[m] = a;
    }
  }
  __syncthreads();

  float w[NNB][NHEADS];
#pragma unroll
  for (int m = 0; m < NHEADS; ++m) {
    const float sm = s_self[m];
    float mx = -1e30f;
#pragma unroll
    for (int k = 0; k < NNB; ++k) {
      float l = sm + s_logit[k][m];
      l = (l >= 0.f) ? l : 0.2f * l;
      w[k][m] = l;
      mx = fmaxf(mx, l);
    }
    float sum = 0.f;
#pragma unroll
    for (int k = 0; k < NNB; ++k) { const float e = expf(w[k][m] - mx); w[k][m] = e; sum += e; }
    const float inv = 1.f / sum;
#pragma unroll
    for (int k = 0; k < NNB; ++k) w[k][m] *= inv;
  }

  bf16_t* agg_n = agg + (size_t)n * (NHEADS * HDIM);
  const int hh = t * 2;
  float e0[NNB], e1[NNB];
#pragma unroll
  for (int k = 0; k < NNB; ++k) { e0[k] = s_hs[k][hh]; e1[k] = s_hs[k][hh + 1]; }
#pragma unroll
  for (int m = 0; m < NHEADS; ++m) {
    float a0 = 0.f, a1 = 0.f;
#pragma unroll
    for (int k = 0; k < NNB; ++k) { a0 += w[k][m] * e0[k]; a1 += w[k][m] * e1[k]; }
    bf16x2 pk; pk[0] = (bf16_t)a0; pk[1] = (bf16_t)a1;
    *(bf16x2*)(agg_n + m * HDIM + hh) = pk;
  }
}

// ---------------------------------------------------------------------------
// GEMM1 (spatial gates): 3-DEEP PIPELINE, counted vmcnt (T3/T4), raw
// s_barrier. RACE FIX vs round 13: s_barrier is IntrNoMem -- LDS ops can be
// compiler-moved across it. Pin buffer hand-off boundaries with
// sched_barrier(0): after barrier#1 (no ds_read hoist -> would race other
// waves' in-flight loads), before barrier#2 (no ds_read sink -> would race
// STAGE overwrite), after barrier#2 (no STAGE hoist). Compute window stays
// freely schedulable. BK=32, tile 128x64, grid 64x16. 4-chunk XOR swizzle
// (verified conflicts == 0). LDS 36 KB -> 4 blocks/CU.
// ---------------------------------------------------------------------------
__global__ __launch_bounds__(256) void gemm1_kernel(
    const bf16_t* __restrict__ A, const bf16_t* __restrict__ Bt,
    const float* __restrict__ b_fg, const float* __restrict__ b_ig,
    const float* __restrict__ c_in, const float* __restrict__ h_in,
    float* __restrict__ cprime, bf16_t* __restrict__ A2)
{
  __shared__ bf16_t At[3][128][32];   // 24 KB
  __shared__ bf16_t Bs[3][64][32];    // 12 KB

  const int tid  = threadIdx.x;
  const int wave = tid >> 6, lane = tid & 63;
  const int wr = wave >> 1, wc = wave & 1;
  const int bm0 = blockIdx.x * 128;
  const int bn0 = blockIdx.y * 64;
  const int K = 2048;

  f32x4 acc[4][2] = {};

  const int srow = tid >> 2;                         // 0..63
  const int sch  = tid & 3;                          // physical 16B chunk
  const int gsw8 = (sch ^ ((srow >> 1) & 3)) * 8;    // pre-swizzled global chunk
  const int sch8 = sch * 8;                          // linear LDS dest
  const int frow = lane & 15;
  const int fro8 = ((lane >> 4) ^ ((frow >> 1) & 3)) * 8;  // swizzled read chunk

  auto STAGE = [&](int buf, int k0) {
    load_lds16(A  + (size_t)(bm0 + srow)      * K + k0 + gsw8, &At[buf][srow][sch8]);
    load_lds16(A  + (size_t)(bm0 + 64 + srow) * K + k0 + gsw8, &At[buf][64 + srow][sch8]);
    load_lds16(Bt + (size_t)(bn0 + srow)      * K + k0 + gsw8, &Bs[buf][srow][sch8]);
  };
  auto COMPUTE = [&](int buf) {
    bf16x8 af[4], bv[2];
#pragma unroll
    for (int i = 0; i < 4; ++i) af[i] = *(const bf16x8*)&At[buf][wr * 64 + i * 16 + frow][fro8];
#pragma unroll
    for (int j = 0; j < 2; ++j) bv[j] = *(const bf16x8*)&Bs[buf][wc * 32 + j * 16 + frow][fro8];
#pragma unroll
    for (int i = 0; i < 4; ++i)
#pragma unroll
      for (int j = 0; j < 2; ++j)
        acc[i][j] = __builtin_amdgcn_mfma_f32_16x16x32_bf16(af[i], bv[j], acc[i][j], 0, 0, 0);
  };
  auto WAIT_BAR = [&](int n_outstanding) {
    if (n_outstanding == 6) asm volatile("s_waitcnt vmcnt(6)" ::: "memory");
    else if (n_outstanding == 3) asm volatile("s_waitcnt vmcnt(3)" ::: "memory");
    else asm volatile("s_waitcnt vmcnt(0)" ::: "memory");
    __builtin_amdgcn_s_barrier();
    __builtin_amdgcn_sched_barrier(0);   // no ds_read hoist above barrier
  };
  auto END_BAR = [&]() {
    __builtin_amdgcn_sched_barrier(0);   // no ds_read sink below barrier
    __builtin_amdgcn_s_barrier();
    __builtin_amdgcn_sched_barrier(0);   // no STAGE hoist above barrier
  };

  const int nt = K >> 5;   // 64
  STAGE(0, 0); STAGE(1, 32); STAGE(2, 64);
  for (int t = 0; t < nt - 3; ++t) {
    WAIT_BAR(6);
    COMPUTE(t % 3);
    END_BAR();
    STAGE(t % 3, (t + 3) * 32);
  }
  WAIT_BAR(6);
  COMPUTE((nt - 3) % 3);
  END_BAR();
  WAIT_BAR(3);
  COMPUTE((nt - 2) % 3);
  END_BAR();
  WAIT_BAR(0);
  COMPUTE((nt - 1) % 3);

  const int col_in = lane & 15;
  const int row_in = (lane >> 4) * 4;
#pragma unroll
  for (int i = 0; i < 4; ++i) {
#pragma unroll
    for (int j = 0; j < 2; ++j) {
      const int col = bn0 + wc * 32 + j * 16 + col_in;
#pragma unroll
      for (int r = 0; r < 4; ++r) {
        const int row = bm0 + wr * 64 + i * 16 + row_in + r;
        const float v = acc[i][j][r];
        if (col < 512) {
          const float s = sigmoidf_(v + b_fg[col]);
          cprime[(size_t)row * 512 + col] = c_in[(size_t)row * 512 + col] * s;
        } else {
          const int jj = col - 512;
          const float s = sigmoidf_(v + b_ig[jj]);
          A2[(size_t)row * 640 + 128 + jj] = (bf16_t)(h_in[(size_t)row * 512 + jj] * s);
        }
      }
    }
  }
}

// ---------------------------------------------------------------------------
// GEMM2 (LSTM gates, fused finish): same 3-deep counted-vmcnt pipeline with
// sched_barrier-pinned hand-offs. BK=32, tile 128x128, grid 64x16, L=4 ->
// vmcnt(8)/(4)/(0). 4-chunk swizzle. Cols gate-interleaved (c=q*4+g).
// Fused LSTM epilogue via two-pass fp32 LDS exchange (union, 48 KB).
// ---------------------------------------------------------------------------
__global__ __launch_bounds__(256) void gemm2_kernel(
    const bf16_t* __restrict__ A, const bf16_t* __restrict__ Bt,
    const float* __restrict__ b2, const float* __restrict__ cprime,
    float* __restrict__ out)
{
  __shared__ union {
    struct { bf16_t A[3][128][32]; bf16_t B[3][128][32]; } st;  // 48 KB
    float epi[64][128];                                         // 32 KB
  } sm;

  const int tid  = threadIdx.x;
  const int wave = tid >> 6, lane = tid & 63;
  const int wr = wave >> 1, wc = wave & 1;
  const int bm0 = blockIdx.x * 128;
  const int bn0 = blockIdx.y * 128;
  const int K = 640;

  f32x4 acc[4][4] = {};

  const int srow = tid >> 2;
  const int sch  = tid & 3;
  const int gsw8 = (sch ^ ((srow >> 1) & 3)) * 8;
  const int sch8 = sch * 8;
  const int frow = lane & 15;
  const int fro8 = ((lane >> 4) ^ ((frow >> 1) & 3)) * 8;

  auto STAGE = [&](int buf, int k0) {
    load_lds16(A  + (size_t)(bm0 + srow)      * K + k0 + gsw8, &sm.st.A[buf][srow][sch8]);
    load_lds16(A  + (size_t)(bm0 + 64 + srow) * K + k0 + gsw8, &sm.st.A[buf][64 + srow][sch8]);
    load_lds16(Bt + (size_t)(bn0 + srow)      * K + k0 + gsw8, &sm.st.B[buf][srow][sch8]);
    load_lds16(Bt + (size_t)(bn0 + 64 + srow) * K + k0 + gsw8, &sm.st.B[buf][64 + srow][sch8]);
  };
  auto COMPUTE = [&](int buf) {
    bf16x8 af[4], bv[4];
#pragma unroll
    for (int i = 0; i < 4; ++i) af[i] = *(const bf16x8*)&sm.st.A[buf][wr * 64 + i * 16 + frow][fro8];
#pragma unroll
    for (int j = 0; j < 4; ++j) bv[j] = *(const bf16x8*)&sm.st.B[buf][wc * 64 + j * 16 + frow][fro8];
#pragma unroll
    for (int i = 0; i < 4; ++i)
#pragma unroll
      for (int j = 0; j < 4; ++j)
        acc[i][j] = __builtin_amdgcn_mfma_f32_16x16x32_bf16(af[i], bv[j], acc[i][j], 0, 0, 0);
  };
  auto WAIT_BAR = [&](int n_outstanding) {
    if (n_outstanding == 8) asm volatile("s_waitcnt vmcnt(8)" ::: "memory");
    else if (n_outstanding == 4) asm volatile("s_waitcnt vmcnt(4)" ::: "memory");
    else asm volatile("s_waitcnt vmcnt(0)" ::: "memory");
    __builtin_amdgcn_s_barrier();
    __builtin_amdgcn_sched_barrier(0);
  };
  auto END_BAR = [&]() {
    __builtin_amdgcn_sched_barrier(0);
    __builtin_amdgcn_s_barrier();
    __builtin_amdgcn_sched_barrier(0);
  };

  const int nt = K >> 5;   // 20
  STAGE(0, 0); STAGE(1, 32); STAGE(2, 64);
  for (int t = 0; t < nt - 3; ++t) {
    WAIT_BAR(8);
    COMPUTE(t % 3);
    END_BAR();
    STAGE(t % 3, (t + 3) * 32);
  }
  WAIT_BAR(8);
  COMPUTE((nt - 3) % 3);
  END_BAR();
  WAIT_BAR(4);
  COMPUTE((nt - 2) % 3);
  END_BAR();
  WAIT_BAR(0);
  COMPUTE((nt - 1) % 3);

  __syncthreads();   // full fence before epi union overwrite

  // Fused LSTM finish: two passes over 64-row halves through fp32 LDS.
  const int col_in = lane & 15;
  const int row_in = (lane >> 4) * 4;
  const int q0i = bn0 >> 2;           // first global q of this block (32 q's)
  const int qi  = tid & 31;           // 0..31
  const int r0  = tid >> 5;           // 0..7

#pragma unroll
  for (int p = 0; p < 2; ++p) {
    if (wr == p) {
#pragma unroll
      for (int i = 0; i < 4; ++i)
#pragma unroll
        for (int j = 0; j < 4; ++j)
#pragma unroll
          for (int r = 0; r < 4; ++r)
            sm.epi[i * 16 + row_in + r][wc * 64 + j * 16 + col_in] = acc[i][j][r];
    }
    __syncthreads();
    const float4 bb = *(const float4*)&b2[(size_t)(q0i + qi) * 4];
#pragma unroll
    for (int rr = 0; rr < 8; ++rr) {
      const int lr = r0 + rr * 8;               // 0..63 local row in this half
      const float4 g4 = *(const float4*)&sm.epi[lr][qi * 4];
      const int grow = bm0 + p * 64 + lr;
      const int q    = q0i + qi;
      const float cp = cprime[(size_t)grow * 512 + q];
      const float ig = sigmoidf_(g4.x + bb.x);
      const float fg = sigmoidf_(g4.y + bb.y);
      const float gg = tanhf(g4.z + bb.z);
      const float og = sigmoidf_(g4.w + bb.w);
      const float cn = fg * cp + ig * gg;
      const float hn = og * tanhf(cn);
      out[(size_t)grow * 512 + q] = hn;
      out[(size_t)N_ROWS * 512 + (size_t)grow * 512 + q] = cn;
    }
    __syncthreads();
  }
}

// ---------------------------------------------------------------------------
extern "C" void kernel_launch(void* const* d_in, const int* in_sizes, int n_in,
                              void* d_out, int out_size, void* d_ws, size_t ws_size,
                              hipStream_t stream) {
  const float* x     = (const float*)d_in[0];
  const float* h     = (const float*)d_in[1];
  const float* c     = (const float*)d_in[2];
  const float* hsp   = (const float*)d_in[3];
  const float* a_src = (const float*)d_in[4];
  const float* w_fg  = (const float*)d_in[5];
  const float* b_fg  = (const float*)d_in[6];
  const float* w_ig  = (const float*)d_in[7];
  const float* b_ig  = (const float*)d_in[8];
  const float* w_ih  = (const float*)d_in[9];
  const float* w_hh  = (const float*)d_in[10];
  const float* b_ih  = (const float*)d_in[11];
  const float* b_hh  = (const float*)d_in[12];
  float* out = (float*)d_out;

  uint8_t* ws = (uint8_t*)d_ws;
  bf16_t* agg    = (bf16_t*)(ws);                 // 8192*2048*2 = 33,554,432
  bf16_t* W1     = (bf16_t*)(ws + 33554432);      // 1024*2048*2 =  4,194,304
  bf16_t* W2i    = (bf16_t*)(ws + 37748736);      // 2048*640*2  =  2,621,440
  float*  b2     = (float*) (ws + 40370176);      // 2048*4      =      8,192
  bf16_t* A2     = (bf16_t*)(ws + 40378368);      // 8192*640*2  = 10,485,760
  float*  cprime = (float*) (ws + 50864128);      // 8192*512*4  = 16,777,216
  // total 67,641,344 bytes

  pack_kernel<<<4360, 256, 0, stream>>>(w_fg, w_ig, w_ih, w_hh, b_ih, b_hh, x,
                                        W1, W2i, b2, A2);
  attn_agg_kernel<<<N_ROWS, 256, 0, stream>>>(h, hsp, a_src, agg);
  gemm1_kernel<<<dim3(64, 16), 256, 0, stream>>>(
      agg, W1, b_fg, b_ig, c, h, cprime, A2);
  gemm2_kernel<<<dim3(64, 16), 256, 0, stream>>>(
      A2, W2i, b2, cprime, out);
}